// Round 1
// baseline (3628.658 us; speedup 1.0000x reference)
//
#include <hip/hip_runtime.h>
#include <hip/hip_bf16.h>

#define NN 100000
#define NE 1200000
#define IND 128
#define HID 64
#define NC 5
#define NG 128

// ---------------- degree / norm ----------------
__global__ __launch_bounds__(256) void k_deg_init(float* __restrict__ deg) {
    int i = blockIdx.x * 256 + threadIdx.x;
    if (i < NN) deg[i] = 1.0f;  // self-loop contributes 1
}

__global__ __launch_bounds__(256) void k_deg_count(const int* __restrict__ dst, float* __restrict__ deg) {
    int i = blockIdx.x * 256 + threadIdx.x;
    if (i < NE) atomicAdd(&deg[dst[i]], 1.0f);
}

__global__ __launch_bounds__(256) void k_dinv(float* __restrict__ deg) {
    int i = blockIdx.x * 256 + threadIdx.x;
    if (i < NN) deg[i] = rsqrtf(deg[i]);  // deg >= 1 always
}

__global__ __launch_bounds__(256) void k_norm(const int* __restrict__ src, const int* __restrict__ dst,
                                              const float* __restrict__ dinv, float* __restrict__ norm) {
    int i = blockIdx.x * 256 + threadIdx.x;
    if (i < NE) norm[i] = dinv[src[i]] * dinv[dst[i]];
}

// ---------------- GEMM: out[n][j] = sum_k X[n][k] * W[k][j] ----------------
// 256 threads = 4 nodes/block, one wave per node, j = lane.
template <int K>
__global__ __launch_bounds__(256) void k_gemm(const float* __restrict__ X, const float* __restrict__ W,
                                              float* __restrict__ out) {
    __shared__ float Wl[K * HID];
    __shared__ float inl[4][K];
    int tid = threadIdx.x;
    int j = tid & 63;
    int local = tid >> 6;
    for (int k = local; k < K; k += 4) Wl[k * HID + j] = W[k * HID + j];
    int node0 = blockIdx.x * 4;
    for (int t = tid; t < 4 * K; t += 256) {
        int nn = t / K, kk = t % K;
        int n = node0 + nn;
        inl[nn][kk] = (n < NN) ? X[n * K + kk] : 0.0f;
    }
    __syncthreads();
    int n = node0 + local;
    if (n >= NN) return;
    float acc = 0.0f;
#pragma unroll
    for (int k = 0; k < K; ++k) acc = fmaf(inl[local][k], Wl[k * HID + j], acc);
    out[n * HID + j] = acc;
}

// ---------------- aggregation ----------------
// agg[n][:] = dinv[n]^2 * hW[n][:]   (self-loop term), float4 over N*HID
__global__ __launch_bounds__(256) void k_agg_init(const float* __restrict__ hW, const float* __restrict__ dinv,
                                                  float* __restrict__ agg) {
    int i = blockIdx.x * 256 + threadIdx.x;  // over NN*16 float4s
    if (i >= NN * 16) return;
    int n = i >> 4;
    float d = dinv[n];
    float s = d * d;
    float4 v = ((const float4*)hW)[i];
    v.x *= s; v.y *= s; v.z *= s; v.w *= s;
    ((float4*)agg)[i] = v;
}

// agg[dst][:] += norm[e] * hW[src][:]  -- one thread per (edge, float4 chunk)
__global__ __launch_bounds__(256) void k_scatter(const float* __restrict__ hW, const int* __restrict__ src,
                                                 const int* __restrict__ dst, const float* __restrict__ norm,
                                                 float* __restrict__ agg) {
    int i = blockIdx.x * 256 + threadIdx.x;  // over NE*16
    if (i >= NE * 16) return;
    int e = i >> 4, q = i & 15;
    int s = src[e], d = dst[e];
    float w = norm[e];
    float4 v = ((const float4*)(hW + s * HID))[q];
    float* a = agg + d * HID + q * 4;
    atomicAdd(a + 0, v.x * w);
    atomicAdd(a + 1, v.y * w);
    atomicAdd(a + 2, v.z * w);
    atomicAdd(a + 3, v.w * w);
}

// agg = relu(agg + b), float4
__global__ __launch_bounds__(256) void k_bias_relu(float* __restrict__ agg, const float* __restrict__ b) {
    int i = blockIdx.x * 256 + threadIdx.x;  // over NN*16 float4s
    if (i >= NN * 16) return;
    int q = i & 15;
    float4 v = ((float4*)agg)[i];
    float4 bv = ((const float4*)b)[q];
    v.x = fmaxf(v.x + bv.x, 0.0f);
    v.y = fmaxf(v.y + bv.y, 0.0f);
    v.z = fmaxf(v.z + bv.z, 0.0f);
    v.w = fmaxf(v.w + bv.w, 0.0f);
    ((float4*)agg)[i] = v;
}

// ---------------- pooling + head ----------------
__global__ __launch_bounds__(256) void k_pool_zero(float* __restrict__ sums, float* __restrict__ counts) {
    int i = blockIdx.x * 256 + threadIdx.x;
    if (i < NG * HID) sums[i] = 0.0f;
    if (i < NG) counts[i] = 0.0f;
}

__global__ __launch_bounds__(256) void k_counts(const int* __restrict__ batch, float* __restrict__ counts) {
    int i = blockIdx.x * 256 + threadIdx.x;
    if (i < NN) atomicAdd(&counts[batch[i]], 1.0f);
}

// batch is sorted: per-block running accumulation, one atomic per segment boundary.
__global__ __launch_bounds__(64) void k_pool(const float* __restrict__ h, const int* __restrict__ batch,
                                             float* __restrict__ sums) {
    int j = threadIdx.x;
    int n0 = blockIdx.x * 256;
    if (n0 >= NN) return;
    int n1 = n0 + 256;
    if (n1 > NN) n1 = NN;
    float acc = 0.0f;
    int cur = batch[n0];
    for (int n = n0; n < n1; ++n) {
        int g = batch[n];
        if (g != cur) {
            atomicAdd(&sums[cur * HID + j], acc);
            acc = 0.0f;
            cur = g;
        }
        acc += h[n * HID + j];
    }
    atomicAdd(&sums[cur * HID + j], acc);
}

__global__ __launch_bounds__(64) void k_head(const float* __restrict__ sums, const float* __restrict__ counts,
                                             const float* __restrict__ Wc, const float* __restrict__ bc,
                                             float* __restrict__ out) {
    int g = blockIdx.x;
    int j = threadIdx.x;
    float cnt = counts[g];
    cnt = cnt > 1.0f ? cnt : 1.0f;
    float p = sums[g * HID + j] / cnt;
#pragma unroll
    for (int c = 0; c < NC; ++c) {
        float v = p * Wc[j * NC + c];
        for (int off = 32; off > 0; off >>= 1) v += __shfl_down(v, off);
        if (j == 0) out[g * NC + c] = v + bc[c];
    }
}

// ---------------- driver ----------------
extern "C" void kernel_launch(void* const* d_in, const int* in_sizes, int n_in,
                              void* d_out, int out_size, void* d_ws, size_t ws_size,
                              hipStream_t stream) {
    const float* x  = (const float*)d_in[0];
    const int* ei   = (const int*)d_in[1];
    const int* bat  = (const int*)d_in[2];
    const float* W1 = (const float*)d_in[3];
    const float* b1 = (const float*)d_in[4];
    const float* W2 = (const float*)d_in[5];
    const float* b2 = (const float*)d_in[6];
    const float* W3 = (const float*)d_in[7];
    const float* b3 = (const float*)d_in[8];
    const float* Wc = (const float*)d_in[9];
    const float* bc = (const float*)d_in[10];
    float* out = (float*)d_out;

    const int* src = ei;
    const int* dst = ei + NE;

    float* ws = (float*)d_ws;
    float* dinv   = ws;                       // NN
    float* norm   = ws + 100000;              // NE
    float* hW     = ws + 1300000;             // NN*HID (16B aligned)
    float* agg    = ws + 7700000;             // NN*HID (16B aligned)
    float* sums   = ws + 14100000;            // NG*HID
    float* counts = ws + 14108192;            // NG

    const int gN   = (NN + 255) / 256;        // 391
    const int gE   = (NE + 255) / 256;        // 4688
    const int gNH4 = NN * 16 / 256;           // 6250
    const int gEH4 = NE * 16 / 256;           // 75000

    // normalization
    k_deg_init<<<gN, 256, 0, stream>>>(dinv);
    k_deg_count<<<gE, 256, 0, stream>>>(dst, dinv);
    k_dinv<<<gN, 256, 0, stream>>>(dinv);
    k_norm<<<gE, 256, 0, stream>>>(src, dst, dinv, norm);

    // layer 1
    k_gemm<IND><<<NN / 4, 256, 0, stream>>>(x, W1, hW);
    k_agg_init<<<gNH4, 256, 0, stream>>>(hW, dinv, agg);
    k_scatter<<<gEH4, 256, 0, stream>>>(hW, src, dst, norm, agg);
    k_bias_relu<<<gNH4, 256, 0, stream>>>(agg, b1);

    // layer 2
    k_gemm<HID><<<NN / 4, 256, 0, stream>>>(agg, W2, hW);
    k_agg_init<<<gNH4, 256, 0, stream>>>(hW, dinv, agg);
    k_scatter<<<gEH4, 256, 0, stream>>>(hW, src, dst, norm, agg);
    k_bias_relu<<<gNH4, 256, 0, stream>>>(agg, b2);

    // layer 3
    k_gemm<HID><<<NN / 4, 256, 0, stream>>>(agg, W3, hW);
    k_agg_init<<<gNH4, 256, 0, stream>>>(hW, dinv, agg);
    k_scatter<<<gEH4, 256, 0, stream>>>(hW, src, dst, norm, agg);
    k_bias_relu<<<gNH4, 256, 0, stream>>>(agg, b3);

    // pooling + head
    k_pool_zero<<<(NG * HID + 255) / 256, 256, 0, stream>>>(sums, counts);
    k_counts<<<gN, 256, 0, stream>>>(bat, counts);
    k_pool<<<gN, 64, 0, stream>>>(agg, bat, sums);
    k_head<<<NG, 64, 0, stream>>>(sums, counts, Wc, bc, out);
}

// Round 2
// 998.360 us; speedup vs baseline: 3.6346x; 3.6346x over previous
//
#include <hip/hip_runtime.h>
#include <hip/hip_bf16.h>

#define NN 100000
#define NE 1200000
#define IND 128
#define HID 64
#define NC 5
#define NG 128
#define NB 391   // ceil(NN/256) blocks for node-sized kernels

// ---------------- CSR build: histogram -> scan -> bucket ----------------
__global__ __launch_bounds__(256) void k_zero_int(int* __restrict__ p, int n) {
    int i = blockIdx.x * 256 + threadIdx.x;
    if (i < n) p[i] = 0;
}

__global__ __launch_bounds__(256) void k_hist(const int* __restrict__ dst, int* __restrict__ cnt) {
    int e = blockIdx.x * 256 + threadIdx.x;
    if (e < NE) atomicAdd(&cnt[dst[e]], 1);
}

// dinv = rsqrt(in_degree + 1)   (self-loop)
__global__ __launch_bounds__(256) void k_dinv(const int* __restrict__ cnt, float* __restrict__ dinv) {
    int i = blockIdx.x * 256 + threadIdx.x;
    if (i < NN) dinv[i] = rsqrtf((float)cnt[i] + 1.0f);
}

// per-block exclusive scan of cnt (256 elems/block) + block totals
__global__ __launch_bounds__(256) void k_scan1(const int* __restrict__ cnt, int* __restrict__ exc,
                                               int* __restrict__ bsum) {
    __shared__ int lds[256];
    int tid = threadIdx.x;
    int i = blockIdx.x * 256 + tid;
    int v = (i < NN) ? cnt[i] : 0;
    lds[tid] = v;
    __syncthreads();
    for (int off = 1; off < 256; off <<= 1) {
        int t = (tid >= off) ? lds[tid - off] : 0;
        __syncthreads();
        lds[tid] += t;
        __syncthreads();
    }
    if (i < NN) exc[i] = lds[tid] - v;
    if (tid == 255) bsum[blockIdx.x] = lds[255];
}

// exclusive scan of the NB block totals (single block)
__global__ __launch_bounds__(512) void k_scan2(int* __restrict__ bsum) {
    __shared__ int lds[512];
    int tid = threadIdx.x;
    int v = (tid < NB) ? bsum[tid] : 0;
    lds[tid] = v;
    __syncthreads();
    for (int off = 1; off < 512; off <<= 1) {
        int t = (tid >= off) ? lds[tid - off] : 0;
        __syncthreads();
        lds[tid] += t;
        __syncthreads();
    }
    if (tid < NB) bsum[tid] = lds[tid] - v;
}

__global__ __launch_bounds__(256) void k_scan3(const int* __restrict__ exc, const int* __restrict__ bsum,
                                               int* __restrict__ row_ptr, int* __restrict__ cursor) {
    int i = blockIdx.x * 256 + threadIdx.x;
    if (i < NN) {
        int r = exc[i] + bsum[blockIdx.x];
        row_ptr[i] = r;
        cursor[i] = r;
    }
    if (i == 0) row_ptr[NN] = NE;
}

__global__ __launch_bounds__(256) void k_bucket(const int* __restrict__ src, const int* __restrict__ dst,
                                                int* __restrict__ cursor, int* __restrict__ src_sorted) {
    int e = blockIdx.x * 256 + threadIdx.x;
    if (e < NE) {
        int pos = atomicAdd(&cursor[dst[e]], 1);
        src_sorted[pos] = src[e];
    }
}

// ---------------- GEMM: out[n][j] = sum_k X[n][k] * W[k][j] ----------------
template <int K>
__global__ __launch_bounds__(256) void k_gemm(const float* __restrict__ X, const float* __restrict__ W,
                                              float* __restrict__ out) {
    __shared__ float Wl[K * HID];
    __shared__ float inl[4][K];
    int tid = threadIdx.x;
    int j = tid & 63;
    int local = tid >> 6;
    for (int k = local; k < K; k += 4) Wl[k * HID + j] = W[k * HID + j];
    int node0 = blockIdx.x * 4;
    for (int t = tid; t < 4 * K; t += 256) {
        int nn = t / K, kk = t % K;
        int n = node0 + nn;
        inl[nn][kk] = (n < NN) ? X[n * K + kk] : 0.0f;
    }
    __syncthreads();
    int n = node0 + local;
    if (n >= NN) return;
    float acc = 0.0f;
#pragma unroll
    for (int k = 0; k < K; ++k) acc = fmaf(inl[local][k], Wl[k * HID + j], acc);
    out[n * HID + j] = acc;
}

// ---------------- fused aggregate: self-loop + CSR gather + bias + relu ----------------
// out[n][j] = relu( dinv[n]^2*hW[n][j] + sum_e dinv[src]*dinv[n]*hW[src][j] + b[j] )
__global__ __launch_bounds__(256) void k_aggregate(const float* __restrict__ hW,
                                                   const int* __restrict__ src_sorted,
                                                   const int* __restrict__ row_ptr,
                                                   const float* __restrict__ dinv,
                                                   const float* __restrict__ b,
                                                   float* __restrict__ out) {
    int tid = threadIdx.x;
    int j = tid & 63;
    int n = blockIdx.x * 4 + (tid >> 6);
    if (n >= NN) return;
    float dn = dinv[n];
    float acc = dn * dn * hW[n * HID + j];
    int beg = row_ptr[n], end = row_ptr[n + 1];
    int e = beg;
    for (; e + 1 < end; e += 2) {
        int s0 = src_sorted[e], s1 = src_sorted[e + 1];
        float w0 = dinv[s0] * dn;
        float w1 = dinv[s1] * dn;
        float h0 = hW[s0 * HID + j];
        float h1 = hW[s1 * HID + j];
        acc = fmaf(w0, h0, acc);
        acc = fmaf(w1, h1, acc);
    }
    if (e < end) {
        int s0 = src_sorted[e];
        acc = fmaf(dinv[s0] * dn, hW[s0 * HID + j], acc);
    }
    out[n * HID + j] = fmaxf(acc + b[j], 0.0f);
}

// ---------------- pooling + head ----------------
__global__ __launch_bounds__(256) void k_pool_zero(float* __restrict__ sums, float* __restrict__ counts) {
    int i = blockIdx.x * 256 + threadIdx.x;
    if (i < NG * HID) sums[i] = 0.0f;
    if (i < NG) counts[i] = 0.0f;
}

__global__ __launch_bounds__(256) void k_counts(const int* __restrict__ batch, float* __restrict__ counts) {
    int i = blockIdx.x * 256 + threadIdx.x;
    if (i < NN) atomicAdd(&counts[batch[i]], 1.0f);
}

// batch is sorted: per-block running accumulation, one atomic per segment boundary.
__global__ __launch_bounds__(64) void k_pool(const float* __restrict__ h, const int* __restrict__ batch,
                                             float* __restrict__ sums) {
    int j = threadIdx.x;
    int n0 = blockIdx.x * 256;
    if (n0 >= NN) return;
    int n1 = n0 + 256;
    if (n1 > NN) n1 = NN;
    float acc = 0.0f;
    int cur = batch[n0];
    for (int n = n0; n < n1; ++n) {
        int g = batch[n];
        if (g != cur) {
            atomicAdd(&sums[cur * HID + j], acc);
            acc = 0.0f;
            cur = g;
        }
        acc += h[n * HID + j];
    }
    atomicAdd(&sums[cur * HID + j], acc);
}

__global__ __launch_bounds__(64) void k_head(const float* __restrict__ sums, const float* __restrict__ counts,
                                             const float* __restrict__ Wc, const float* __restrict__ bc,
                                             float* __restrict__ out) {
    int g = blockIdx.x;
    int j = threadIdx.x;
    float cnt = counts[g];
    cnt = cnt > 1.0f ? cnt : 1.0f;
    float p = sums[g * HID + j] / cnt;
#pragma unroll
    for (int c = 0; c < NC; ++c) {
        float v = p * Wc[j * NC + c];
        for (int off = 32; off > 0; off >>= 1) v += __shfl_down(v, off);
        if (j == 0) out[g * NC + c] = v + bc[c];
    }
}

// ---------------- driver ----------------
extern "C" void kernel_launch(void* const* d_in, const int* in_sizes, int n_in,
                              void* d_out, int out_size, void* d_ws, size_t ws_size,
                              hipStream_t stream) {
    const float* x  = (const float*)d_in[0];
    const int* ei   = (const int*)d_in[1];
    const int* bat  = (const int*)d_in[2];
    const float* W1 = (const float*)d_in[3];
    const float* b1 = (const float*)d_in[4];
    const float* W2 = (const float*)d_in[5];
    const float* b2 = (const float*)d_in[6];
    const float* W3 = (const float*)d_in[7];
    const float* b3 = (const float*)d_in[8];
    const float* Wc = (const float*)d_in[9];
    const float* bc = (const float*)d_in[10];
    float* out = (float*)d_out;

    const int* src = ei;
    const int* dst = ei + NE;

    // workspace layout (4-byte elements; hW/agg offsets are 16B-aligned)
    char* wsb = (char*)d_ws;
    float* dinv      = (float*)wsb;                       // NN
    int*   cnt       = (int*)(wsb + 4 *  100000);         // NN
    int*   exc       = (int*)(wsb + 4 *  200000);         // NN
    int*   bsum      = (int*)(wsb + 4 *  300000);         // 512
    int*   row_ptr   = (int*)(wsb + 4 *  300512);         // NN+1
    int*   cursor    = (int*)(wsb + 4 *  400516);         // NN
    int*   srcs      = (int*)(wsb + 4 *  500516);         // NE
    float* hW        = (float*)(wsb + 4 * 1700516);       // NN*HID
    float* agg       = (float*)(wsb + 4 * 8100516);       // NN*HID
    float* sums      = (float*)(wsb + 4 * 14500516);      // NG*HID
    float* counts    = (float*)(wsb + 4 * 14508708);      // NG

    const int gE = (NE + 255) / 256;  // 4688

    // CSR build + normalization
    k_zero_int<<<NB, 256, 0, stream>>>(cnt, NN);
    k_hist<<<gE, 256, 0, stream>>>(dst, cnt);
    k_dinv<<<NB, 256, 0, stream>>>(cnt, dinv);
    k_scan1<<<NB, 256, 0, stream>>>(cnt, exc, bsum);
    k_scan2<<<1, 512, 0, stream>>>(bsum);
    k_scan3<<<NB, 256, 0, stream>>>(exc, bsum, row_ptr, cursor);
    k_bucket<<<gE, 256, 0, stream>>>(src, dst, cursor, srcs);

    // layer 1
    k_gemm<IND><<<NN / 4, 256, 0, stream>>>(x, W1, hW);
    k_aggregate<<<NN / 4, 256, 0, stream>>>(hW, srcs, row_ptr, dinv, b1, agg);
    // layer 2
    k_gemm<HID><<<NN / 4, 256, 0, stream>>>(agg, W2, hW);
    k_aggregate<<<NN / 4, 256, 0, stream>>>(hW, srcs, row_ptr, dinv, b2, agg);
    // layer 3
    k_gemm<HID><<<NN / 4, 256, 0, stream>>>(agg, W3, hW);
    k_aggregate<<<NN / 4, 256, 0, stream>>>(hW, srcs, row_ptr, dinv, b3, agg);

    // pooling + head
    k_pool_zero<<<(NG * HID + 255) / 256, 256, 0, stream>>>(sums, counts);
    k_counts<<<NB, 256, 0, stream>>>(bat, counts);
    k_pool<<<NB, 64, 0, stream>>>(agg, bat, sums);
    k_head<<<NG, 64, 0, stream>>>(sums, counts, Wc, bc, out);
}

// Round 3
// 669.997 us; speedup vs baseline: 5.4159x; 1.4901x over previous
//
#include <hip/hip_runtime.h>
#include <hip/hip_bf16.h>

#define NN 100000
#define NE 1200000
#define IND 128
#define HID 64
#define NC 5
#define NG 128
#define NB 391   // ceil(NN/256)

// ---------------- CSR build: histogram -> scan -> bucket ----------------
__global__ __launch_bounds__(256) void k_zero_int(int* __restrict__ p, int n) {
    int i = blockIdx.x * 256 + threadIdx.x;
    if (i < n) p[i] = 0;
}

__global__ __launch_bounds__(256) void k_hist(const int* __restrict__ dst, int* __restrict__ cnt) {
    int e = blockIdx.x * 256 + threadIdx.x;
    if (e < NE) atomicAdd(&cnt[dst[e]], 1);
}

// dinv = rsqrt(in_degree + 1)   (self-loop)
__global__ __launch_bounds__(256) void k_dinv(const int* __restrict__ cnt, float* __restrict__ dinv) {
    int i = blockIdx.x * 256 + threadIdx.x;
    if (i < NN) dinv[i] = rsqrtf((float)cnt[i] + 1.0f);
}

// per-block exclusive scan of cnt (256 elems/block) + block totals
__global__ __launch_bounds__(256) void k_scan1(const int* __restrict__ cnt, int* __restrict__ exc,
                                               int* __restrict__ bsum) {
    __shared__ int lds[256];
    int tid = threadIdx.x;
    int i = blockIdx.x * 256 + tid;
    int v = (i < NN) ? cnt[i] : 0;
    lds[tid] = v;
    __syncthreads();
    for (int off = 1; off < 256; off <<= 1) {
        int t = (tid >= off) ? lds[tid - off] : 0;
        __syncthreads();
        lds[tid] += t;
        __syncthreads();
    }
    if (i < NN) exc[i] = lds[tid] - v;
    if (tid == 255) bsum[blockIdx.x] = lds[255];
}

// exclusive scan of the NB block totals (single block)
__global__ __launch_bounds__(512) void k_scan2(int* __restrict__ bsum) {
    __shared__ int lds[512];
    int tid = threadIdx.x;
    int v = (tid < NB) ? bsum[tid] : 0;
    lds[tid] = v;
    __syncthreads();
    for (int off = 1; off < 512; off <<= 1) {
        int t = (tid >= off) ? lds[tid - off] : 0;
        __syncthreads();
        lds[tid] += t;
        __syncthreads();
    }
    if (tid < NB) bsum[tid] = lds[tid] - v;
}

__global__ __launch_bounds__(256) void k_scan3(const int* __restrict__ exc, const int* __restrict__ bsum,
                                               int* __restrict__ row_ptr, int* __restrict__ cursor) {
    int i = blockIdx.x * 256 + threadIdx.x;
    if (i < NN) {
        int r = exc[i] + bsum[blockIdx.x];
        row_ptr[i] = r;
        cursor[i] = r;
    }
    if (i == 0) row_ptr[NN] = NE;
}

__global__ __launch_bounds__(256) void k_bucket(const int* __restrict__ src, const int* __restrict__ dst,
                                                int* __restrict__ cursor, int* __restrict__ src_sorted) {
    int e = blockIdx.x * 256 + threadIdx.x;
    if (e < NE) {
        int pos = atomicAdd(&cursor[dst[e]], 1);
        src_sorted[pos] = src[e];
    }
}

// ---------------- GEMM: out[n][j] = sum_k X[n][k] * W[k][j] ----------------
template <int K>
__global__ __launch_bounds__(256) void k_gemm(const float* __restrict__ X, const float* __restrict__ W,
                                              float* __restrict__ out) {
    __shared__ float Wl[K * HID];
    __shared__ float inl[4][K];
    int tid = threadIdx.x;
    int j = tid & 63;
    int local = tid >> 6;
    for (int k = local; k < K; k += 4) Wl[k * HID + j] = W[k * HID + j];
    int node0 = blockIdx.x * 4;
    for (int t = tid; t < 4 * K; t += 256) {
        int nn = t / K, kk = t % K;
        int n = node0 + nn;
        inl[nn][kk] = (n < NN) ? X[n * K + kk] : 0.0f;
    }
    __syncthreads();
    int n = node0 + local;
    if (n >= NN) return;
    float acc = 0.0f;
#pragma unroll
    for (int k = 0; k < K; ++k) acc = fmaf(inl[local][k], Wl[k * HID + j], acc);
    out[n * HID + j] = acc;
}

// ---------------- fused aggregate: self-loop + CSR gather + bias + relu ----------------
__global__ __launch_bounds__(256) void k_aggregate(const float* __restrict__ hW,
                                                   const int* __restrict__ src_sorted,
                                                   const int* __restrict__ row_ptr,
                                                   const float* __restrict__ dinv,
                                                   const float* __restrict__ b,
                                                   float* __restrict__ out) {
    int tid = threadIdx.x;
    int j = tid & 63;
    int n = blockIdx.x * 4 + (tid >> 6);
    if (n >= NN) return;
    float dn = dinv[n];
    float acc = dn * dn * hW[n * HID + j];
    int beg = row_ptr[n], end = row_ptr[n + 1];
    int e = beg;
    for (; e + 1 < end; e += 2) {
        int s0 = src_sorted[e], s1 = src_sorted[e + 1];
        float w0 = dinv[s0] * dn;
        float w1 = dinv[s1] * dn;
        float h0 = hW[s0 * HID + j];
        float h1 = hW[s1 * HID + j];
        acc = fmaf(w0, h0, acc);
        acc = fmaf(w1, h1, acc);
    }
    if (e < end) {
        int s0 = src_sorted[e];
        acc = fmaf(dinv[s0] * dn, hW[s0 * HID + j], acc);
    }
    out[n * HID + j] = fmaxf(acc + b[j], 0.0f);
}

// ---------------- pooling: batch sorted -> segment starts, then fused pool+head ----------------
__global__ __launch_bounds__(256) void k_bounds(const int* __restrict__ batch, int* __restrict__ start) {
    int i = blockIdx.x * 256 + threadIdx.x;
    if (i >= NN) return;
    int b = batch[i];
    if (i == 0) {
        for (int g = 0; g <= b; ++g) start[g] = 0;
    } else {
        int p = batch[i - 1];
        for (int g = p + 1; g <= b; ++g) start[g] = i;
    }
    if (i == NN - 1) {
        for (int g = b + 1; g <= NG; ++g) start[g] = NN;
    }
}

// block g: mean-pool nodes [start[g], start[g+1]) then head -> out[g][0..NC)
__global__ __launch_bounds__(256) void k_pool_head(const float* __restrict__ h, const int* __restrict__ start,
                                                   const float* __restrict__ Wc, const float* __restrict__ bc,
                                                   float* __restrict__ out) {
    __shared__ float part[4][HID];
    int g = blockIdx.x;
    int tid = threadIdx.x;
    int j = tid & 63, w = tid >> 6;
    int beg = start[g], end = start[g + 1];
    float acc = 0.0f;
    for (int n = beg + w; n < end; n += 4) acc += h[n * HID + j];
    part[w][j] = acc;
    __syncthreads();
    if (w == 0) {
        float s = part[0][j] + part[1][j] + part[2][j] + part[3][j];
        float cnt = (float)(end - beg);
        float p = s / fmaxf(cnt, 1.0f);
#pragma unroll
        for (int c = 0; c < NC; ++c) {
            float v = p * Wc[j * NC + c];
            for (int off = 32; off > 0; off >>= 1) v += __shfl_down(v, off);
            if (j == 0) out[g * NC + c] = v + bc[c];
        }
    }
}

// ---------------- driver ----------------
extern "C" void kernel_launch(void* const* d_in, const int* in_sizes, int n_in,
                              void* d_out, int out_size, void* d_ws, size_t ws_size,
                              hipStream_t stream) {
    const float* x  = (const float*)d_in[0];
    const int* ei   = (const int*)d_in[1];
    const int* bat  = (const int*)d_in[2];
    const float* W1 = (const float*)d_in[3];
    const float* b1 = (const float*)d_in[4];
    const float* W2 = (const float*)d_in[5];
    const float* b2 = (const float*)d_in[6];
    const float* W3 = (const float*)d_in[7];
    const float* b3 = (const float*)d_in[8];
    const float* Wc = (const float*)d_in[9];
    const float* bc = (const float*)d_in[10];
    float* out = (float*)d_out;

    const int* src = ei;
    const int* dst = ei + NE;

    char* wsb = (char*)d_ws;
    float* dinv      = (float*)wsb;                       // NN
    int*   cnt       = (int*)(wsb + 4 *  100000);         // NN
    int*   exc       = (int*)(wsb + 4 *  200000);         // NN
    int*   bsum      = (int*)(wsb + 4 *  300000);         // 512
    int*   row_ptr   = (int*)(wsb + 4 *  300512);         // NN+1
    int*   cursor    = (int*)(wsb + 4 *  400516);         // NN
    int*   srcs      = (int*)(wsb + 4 *  500516);         // NE
    float* hW        = (float*)(wsb + 4 * 1700516);       // NN*HID
    float* agg       = (float*)(wsb + 4 * 8100516);       // NN*HID
    int*   start     = (int*)(wsb + 4 * 14500516);        // NG+1

    const int gE = (NE + 255) / 256;  // 4688

    // CSR build + normalization
    k_zero_int<<<NB, 256, 0, stream>>>(cnt, NN);
    k_hist<<<gE, 256, 0, stream>>>(dst, cnt);
    k_dinv<<<NB, 256, 0, stream>>>(cnt, dinv);
    k_scan1<<<NB, 256, 0, stream>>>(cnt, exc, bsum);
    k_scan2<<<1, 512, 0, stream>>>(bsum);
    k_scan3<<<NB, 256, 0, stream>>>(exc, bsum, row_ptr, cursor);
    k_bucket<<<gE, 256, 0, stream>>>(src, dst, cursor, srcs);

    // layers
    k_gemm<IND><<<NN / 4, 256, 0, stream>>>(x, W1, hW);
    k_aggregate<<<NN / 4, 256, 0, stream>>>(hW, srcs, row_ptr, dinv, b1, agg);
    k_gemm<HID><<<NN / 4, 256, 0, stream>>>(agg, W2, hW);
    k_aggregate<<<NN / 4, 256, 0, stream>>>(hW, srcs, row_ptr, dinv, b2, agg);
    k_gemm<HID><<<NN / 4, 256, 0, stream>>>(agg, W3, hW);
    k_aggregate<<<NN / 4, 256, 0, stream>>>(hW, srcs, row_ptr, dinv, b3, agg);

    // pooling + head (batch is sorted: boundary marks, no atomics)
    k_bounds<<<NB, 256, 0, stream>>>(bat, start);
    k_pool_head<<<NG, 256, 0, stream>>>(agg, start, Wc, bc, out);
}

// Round 4
// 541.413 us; speedup vs baseline: 6.7022x; 1.2375x over previous
//
#include <hip/hip_runtime.h>
#include <hip/hip_bf16.h>

#define NN 100000
#define NE 1200000
#define IND 128
#define HID 64
#define NC 5
#define NG 128
#define NB 391   // ceil(NN/256)

// ---------------- CSR build: histogram -> scan -> bucket ----------------
__global__ __launch_bounds__(256) void k_zero_int(int* __restrict__ p, int n) {
    int i = blockIdx.x * 256 + threadIdx.x;
    if (i < n) p[i] = 0;
}

__global__ __launch_bounds__(256) void k_hist(const int* __restrict__ dst, int* __restrict__ cnt) {
    int e = blockIdx.x * 256 + threadIdx.x;
    if (e < NE) atomicAdd(&cnt[dst[e]], 1);
}

__global__ __launch_bounds__(256) void k_dinv(const int* __restrict__ cnt, float* __restrict__ dinv) {
    int i = blockIdx.x * 256 + threadIdx.x;
    if (i < NN) dinv[i] = rsqrtf((float)cnt[i] + 1.0f);
}

__global__ __launch_bounds__(256) void k_scan1(const int* __restrict__ cnt, int* __restrict__ exc,
                                               int* __restrict__ bsum) {
    __shared__ int lds[256];
    int tid = threadIdx.x;
    int i = blockIdx.x * 256 + tid;
    int v = (i < NN) ? cnt[i] : 0;
    lds[tid] = v;
    __syncthreads();
    for (int off = 1; off < 256; off <<= 1) {
        int t = (tid >= off) ? lds[tid - off] : 0;
        __syncthreads();
        lds[tid] += t;
        __syncthreads();
    }
    if (i < NN) exc[i] = lds[tid] - v;
    if (tid == 255) bsum[blockIdx.x] = lds[255];
}

__global__ __launch_bounds__(512) void k_scan2(int* __restrict__ bsum) {
    __shared__ int lds[512];
    int tid = threadIdx.x;
    int v = (tid < NB) ? bsum[tid] : 0;
    lds[tid] = v;
    __syncthreads();
    for (int off = 1; off < 512; off <<= 1) {
        int t = (tid >= off) ? lds[tid - off] : 0;
        __syncthreads();
        lds[tid] += t;
        __syncthreads();
    }
    if (tid < NB) bsum[tid] = lds[tid] - v;
}

__global__ __launch_bounds__(256) void k_scan3(const int* __restrict__ exc, const int* __restrict__ bsum,
                                               int* __restrict__ row_ptr, int* __restrict__ cursor) {
    int i = blockIdx.x * 256 + threadIdx.x;
    if (i < NN) {
        int r = exc[i] + bsum[blockIdx.x];
        row_ptr[i] = r;
        cursor[i] = r;
    }
    if (i == 0) row_ptr[NN] = NE;
}

__global__ __launch_bounds__(256) void k_bucket(const int* __restrict__ src, const int* __restrict__ dst,
                                                int* __restrict__ cursor, int* __restrict__ src_sorted) {
    int e = blockIdx.x * 256 + threadIdx.x;
    if (e < NE) {
        int pos = atomicAdd(&cursor[dst[e]], 1);
        src_sorted[pos] = src[e];
    }
}

// ---------------- register-tiled GEMM: out[n][j] = sum_k X[n][k] * W[k][j] ----------------
// Block: 256 threads. Thread owns cols {c, c+32}, node slot s covers NR nodes.
// MT nodes/block; MT = NR*8. LDS: W [K][64] + x tile [MT][K].
template <int K, int MT>
__global__ __launch_bounds__(256) void k_gemm(const float* __restrict__ X, const float* __restrict__ W,
                                              float* __restrict__ out) {
    constexpr int NR = MT / 8;
    __shared__ float Wl[K * HID];
    __shared__ float xl[MT * K];
    int tid = threadIdx.x;
    int c = tid & 31;
    int s = tid >> 5;          // node slot 0..7
    int n0 = blockIdx.x * MT;

    // stage W (float4, coalesced)
    {
        const float4* Wg = (const float4*)W;
        float4* Wl4 = (float4*)Wl;
#pragma unroll
        for (int i = 0; i < K * 16 / 256; ++i) Wl4[i * 256 + tid] = Wg[i * 256 + tid];
    }
    // stage x tile (float4, coalesced, guarded)
    {
        const float4* Xg = (const float4*)X;
        float4* xl4 = (float4*)xl;
        const float4 z = {0.f, 0.f, 0.f, 0.f};
#pragma unroll
        for (int i = 0; i < MT * K / 4 / 256; ++i) {
            int idx = i * 256 + tid;
            int node = n0 + idx / (K / 4);
            xl4[idx] = (node < NN) ? Xg[(size_t)n0 * (K / 4) + idx] : z;
        }
    }
    __syncthreads();

    float acc[NR][2];
#pragma unroll
    for (int r = 0; r < NR; ++r) { acc[r][0] = 0.f; acc[r][1] = 0.f; }

#pragma unroll 4
    for (int k0 = 0; k0 < K; k0 += 4) {
        float4 xv[NR];
#pragma unroll
        for (int r = 0; r < NR; ++r)
            xv[r] = *(const float4*)&xl[(s * NR + r) * K + k0];
#pragma unroll
        for (int kk = 0; kk < 4; ++kk) {
            float w0 = Wl[(k0 + kk) * HID + c];
            float w1 = Wl[(k0 + kk) * HID + c + 32];
#pragma unroll
            for (int r = 0; r < NR; ++r) {
                float xe = (kk == 0) ? xv[r].x : (kk == 1) ? xv[r].y : (kk == 2) ? xv[r].z : xv[r].w;
                acc[r][0] = fmaf(xe, w0, acc[r][0]);
                acc[r][1] = fmaf(xe, w1, acc[r][1]);
            }
        }
    }

#pragma unroll
    for (int r = 0; r < NR; ++r) {
        int n = n0 + s * NR + r;
        if (n < NN) {
            out[n * HID + c] = acc[r][0];
            out[n * HID + c + 32] = acc[r][1];
        }
    }
}

// ---------------- fused aggregate: self-loop + CSR gather + bias + relu ----------------
__global__ __launch_bounds__(256) void k_aggregate(const float* __restrict__ hW,
                                                   const int* __restrict__ src_sorted,
                                                   const int* __restrict__ row_ptr,
                                                   const float* __restrict__ dinv,
                                                   const float* __restrict__ b,
                                                   float* __restrict__ out) {
    int tid = threadIdx.x;
    int j = tid & 63;
    int n = blockIdx.x * 4 + (tid >> 6);
    if (n >= NN) return;
    float dn = dinv[n];
    float acc = dn * dn * hW[n * HID + j];
    int beg = row_ptr[n], end = row_ptr[n + 1];
    int e = beg;
    for (; e + 1 < end; e += 2) {
        int s0 = src_sorted[e], s1 = src_sorted[e + 1];
        float w0 = dinv[s0] * dn;
        float w1 = dinv[s1] * dn;
        float h0 = hW[s0 * HID + j];
        float h1 = hW[s1 * HID + j];
        acc = fmaf(w0, h0, acc);
        acc = fmaf(w1, h1, acc);
    }
    if (e < end) {
        int s0 = src_sorted[e];
        acc = fmaf(dinv[s0] * dn, hW[s0 * HID + j], acc);
    }
    out[n * HID + j] = fmaxf(acc + b[j], 0.0f);
}

// ---------------- pooling: segment starts, fused pool+head ----------------
__global__ __launch_bounds__(256) void k_bounds(const int* __restrict__ batch, int* __restrict__ start) {
    int i = blockIdx.x * 256 + threadIdx.x;
    if (i >= NN) return;
    int b = batch[i];
    if (i == 0) {
        for (int g = 0; g <= b; ++g) start[g] = 0;
    } else {
        int p = batch[i - 1];
        for (int g = p + 1; g <= b; ++g) start[g] = i;
    }
    if (i == NN - 1) {
        for (int g = b + 1; g <= NG; ++g) start[g] = NN;
    }
}

__global__ __launch_bounds__(256) void k_pool_head(const float* __restrict__ h, const int* __restrict__ start,
                                                   const float* __restrict__ Wc, const float* __restrict__ bc,
                                                   float* __restrict__ out) {
    __shared__ float part[4][HID];
    int g = blockIdx.x;
    int tid = threadIdx.x;
    int j = tid & 63, w = tid >> 6;
    int beg = start[g], end = start[g + 1];
    float acc = 0.0f;
    for (int n = beg + w; n < end; n += 4) acc += h[n * HID + j];
    part[w][j] = acc;
    __syncthreads();
    if (w == 0) {
        float s = part[0][j] + part[1][j] + part[2][j] + part[3][j];
        float cnt = (float)(end - beg);
        float p = s / fmaxf(cnt, 1.0f);
#pragma unroll
        for (int c = 0; c < NC; ++c) {
            float v = p * Wc[j * NC + c];
            for (int off = 32; off > 0; off >>= 1) v += __shfl_down(v, off);
            if (j == 0) out[g * NC + c] = v + bc[c];
        }
    }
}

// ---------------- driver ----------------
extern "C" void kernel_launch(void* const* d_in, const int* in_sizes, int n_in,
                              void* d_out, int out_size, void* d_ws, size_t ws_size,
                              hipStream_t stream) {
    const float* x  = (const float*)d_in[0];
    const int* ei   = (const int*)d_in[1];
    const int* bat  = (const int*)d_in[2];
    const float* W1 = (const float*)d_in[3];
    const float* b1 = (const float*)d_in[4];
    const float* W2 = (const float*)d_in[5];
    const float* b2 = (const float*)d_in[6];
    const float* W3 = (const float*)d_in[7];
    const float* b3 = (const float*)d_in[8];
    const float* Wc = (const float*)d_in[9];
    const float* bc = (const float*)d_in[10];
    float* out = (float*)d_out;

    const int* src = ei;
    const int* dst = ei + NE;

    char* wsb = (char*)d_ws;
    float* dinv      = (float*)wsb;                       // NN
    int*   cnt       = (int*)(wsb + 4 *  100000);         // NN
    int*   exc       = (int*)(wsb + 4 *  200000);         // NN
    int*   bsum      = (int*)(wsb + 4 *  300000);         // 512
    int*   row_ptr   = (int*)(wsb + 4 *  300512);         // NN+1
    int*   cursor    = (int*)(wsb + 4 *  400516);         // NN
    int*   srcs      = (int*)(wsb + 4 *  500516);         // NE
    float* hW        = (float*)(wsb + 4 * 1700516);       // NN*HID
    float* agg       = (float*)(wsb + 4 * 8100516);       // NN*HID
    int*   start     = (int*)(wsb + 4 * 14500516);        // NG+1

    const int gE = (NE + 255) / 256;  // 4688

    // CSR build + normalization
    k_zero_int<<<NB, 256, 0, stream>>>(cnt, NN);
    k_hist<<<gE, 256, 0, stream>>>(dst, cnt);
    k_dinv<<<NB, 256, 0, stream>>>(cnt, dinv);
    k_scan1<<<NB, 256, 0, stream>>>(cnt, exc, bsum);
    k_scan2<<<1, 512, 0, stream>>>(bsum);
    k_scan3<<<NB, 256, 0, stream>>>(exc, bsum, row_ptr, cursor);
    k_bucket<<<gE, 256, 0, stream>>>(src, dst, cursor, srcs);

    // layers (GEMM grids: ceil(NN/MT))
    k_gemm<IND, 32><<<(NN + 31) / 32, 256, 0, stream>>>(x, W1, hW);
    k_aggregate<<<NN / 4, 256, 0, stream>>>(hW, srcs, row_ptr, dinv, b1, agg);
    k_gemm<HID, 64><<<(NN + 63) / 64, 256, 0, stream>>>(agg, W2, hW);
    k_aggregate<<<NN / 4, 256, 0, stream>>>(hW, srcs, row_ptr, dinv, b2, agg);
    k_gemm<HID, 64><<<(NN + 63) / 64, 256, 0, stream>>>(agg, W3, hW);
    k_aggregate<<<NN / 4, 256, 0, stream>>>(hW, srcs, row_ptr, dinv, b3, agg);

    // pooling + head
    k_bounds<<<NB, 256, 0, stream>>>(bat, start);
    k_pool_head<<<NG, 256, 0, stream>>>(agg, start, Wc, bc, out);
}

// Round 5
// 398.409 us; speedup vs baseline: 9.1079x; 1.3589x over previous
//
#include <hip/hip_runtime.h>
#include <hip/hip_bf16.h>

#define NN 100000
#define NE 1200000
#define IND 128
#define HID 64
#define NC 5
#define NG 128
#define NB 391   // ceil(NN/256)

static __device__ __forceinline__ float bf2f(unsigned short u) {
    union { unsigned int i; float f; } x;
    x.i = (unsigned int)u << 16;
    return x.f;
}
static __device__ __forceinline__ unsigned short f2bf(float f) {
    union { float f; unsigned int i; } x;
    x.f = f;
    unsigned int r = (x.i + 0x7fffu + ((x.i >> 16) & 1u)) >> 16;  // RNE
    return (unsigned short)r;
}

// ---------------- CSR build: histogram(+rank) -> scan -> bucket ----------------
__global__ __launch_bounds__(256) void k_zero_int(int* __restrict__ p, int n) {
    int i = blockIdx.x * 256 + threadIdx.x;
    if (i < n) p[i] = 0;
}

// cnt[d]++ and remember each edge's arrival rank (makes the bucket pass atomic-free)
__global__ __launch_bounds__(256) void k_hist(const int* __restrict__ dst, int* __restrict__ cnt,
                                              int* __restrict__ rank) {
    int e = blockIdx.x * 256 + threadIdx.x;
    if (e < NE) rank[e] = atomicAdd(&cnt[dst[e]], 1);
}

__global__ __launch_bounds__(256) void k_dinv(const int* __restrict__ cnt, float* __restrict__ dinv) {
    int i = blockIdx.x * 256 + threadIdx.x;
    if (i < NN) dinv[i] = rsqrtf((float)cnt[i] + 1.0f);
}

__global__ __launch_bounds__(256) void k_scan1(const int* __restrict__ cnt, int* __restrict__ exc,
                                               int* __restrict__ bsum) {
    __shared__ int lds[256];
    int tid = threadIdx.x;
    int i = blockIdx.x * 256 + tid;
    int v = (i < NN) ? cnt[i] : 0;
    lds[tid] = v;
    __syncthreads();
    for (int off = 1; off < 256; off <<= 1) {
        int t = (tid >= off) ? lds[tid - off] : 0;
        __syncthreads();
        lds[tid] += t;
        __syncthreads();
    }
    if (i < NN) exc[i] = lds[tid] - v;
    if (tid == 255) bsum[blockIdx.x] = lds[255];
}

__global__ __launch_bounds__(512) void k_scan2(int* __restrict__ bsum) {
    __shared__ int lds[512];
    int tid = threadIdx.x;
    int v = (tid < NB) ? bsum[tid] : 0;
    lds[tid] = v;
    __syncthreads();
    for (int off = 1; off < 512; off <<= 1) {
        int t = (tid >= off) ? lds[tid - off] : 0;
        __syncthreads();
        lds[tid] += t;
        __syncthreads();
    }
    if (tid < NB) bsum[tid] = lds[tid] - v;
}

__global__ __launch_bounds__(256) void k_scan3(const int* __restrict__ exc, const int* __restrict__ bsum,
                                               int* __restrict__ row_ptr) {
    int i = blockIdx.x * 256 + threadIdx.x;
    if (i < NN) row_ptr[i] = exc[i] + bsum[blockIdx.x];
    if (i == 0) row_ptr[NN] = NE;
}

// atomic-free scatter: pos = row_ptr[dst] + rank
__global__ __launch_bounds__(256) void k_bucket(const int* __restrict__ src, const int* __restrict__ dst,
                                                const int* __restrict__ row_ptr, const int* __restrict__ rank,
                                                int* __restrict__ src_sorted) {
    int e = blockIdx.x * 256 + threadIdx.x;
    if (e < NE) src_sorted[row_ptr[dst[e]] + rank[e]] = src[e];
}

// ---------------- register-tiled GEMM, epilogue: *dinv, store bf16 ----------------
// out_bf[n][j] = dinv[n] * sum_k X[n][k]*W[k][j]
template <int K, int MT>
__global__ __launch_bounds__(256) void k_gemm(const float* __restrict__ X, const float* __restrict__ W,
                                              const float* __restrict__ dinv,
                                              unsigned short* __restrict__ out_bf) {
    constexpr int NR = MT / 8;
    __shared__ float Wl[K * HID];
    __shared__ float xl[MT * K];
    int tid = threadIdx.x;
    int c = tid & 31;
    int s = tid >> 5;          // node slot 0..7
    int n0 = blockIdx.x * MT;

    {
        const float4* Wg = (const float4*)W;
        float4* Wl4 = (float4*)Wl;
#pragma unroll
        for (int i = 0; i < K * 16 / 256; ++i) Wl4[i * 256 + tid] = Wg[i * 256 + tid];
    }
    {
        const float4* Xg = (const float4*)X;
        float4* xl4 = (float4*)xl;
        const float4 z = {0.f, 0.f, 0.f, 0.f};
#pragma unroll
        for (int i = 0; i < MT * K / 4 / 256; ++i) {
            int idx = i * 256 + tid;
            int node = n0 + idx / (K / 4);
            xl4[idx] = (node < NN) ? Xg[(size_t)n0 * (K / 4) + idx] : z;
        }
    }
    __syncthreads();

    float acc[NR][2];
#pragma unroll
    for (int r = 0; r < NR; ++r) { acc[r][0] = 0.f; acc[r][1] = 0.f; }

#pragma unroll 4
    for (int k0 = 0; k0 < K; k0 += 4) {
        float4 xv[NR];
#pragma unroll
        for (int r = 0; r < NR; ++r)
            xv[r] = *(const float4*)&xl[(s * NR + r) * K + k0];
#pragma unroll
        for (int kk = 0; kk < 4; ++kk) {
            float w0 = Wl[(k0 + kk) * HID + c];
            float w1 = Wl[(k0 + kk) * HID + c + 32];
#pragma unroll
            for (int r = 0; r < NR; ++r) {
                float xe = (kk == 0) ? xv[r].x : (kk == 1) ? xv[r].y : (kk == 2) ? xv[r].z : xv[r].w;
                acc[r][0] = fmaf(xe, w0, acc[r][0]);
                acc[r][1] = fmaf(xe, w1, acc[r][1]);
            }
        }
    }

#pragma unroll
    for (int r = 0; r < NR; ++r) {
        int n = n0 + s * NR + r;
        if (n < NN) {
            float dn = dinv[n];
            out_bf[n * HID + c]      = f2bf(acc[r][0] * dn);
            out_bf[n * HID + c + 32] = f2bf(acc[r][1] * dn);
        }
    }
}

// ---------------- fused aggregate: out[n][j] = relu(dinv[n]*(hWs[n][j]+sum hWs[src][j]) + b[j]) ----------------
__global__ __launch_bounds__(256) void k_aggregate(const unsigned short* __restrict__ hWs,
                                                   const int* __restrict__ src_sorted,
                                                   const int* __restrict__ row_ptr,
                                                   const float* __restrict__ dinv,
                                                   const float* __restrict__ b,
                                                   float* __restrict__ out) {
    int tid = threadIdx.x;
    int j = tid & 63;
    int n = blockIdx.x * 4 + (tid >> 6);
    if (n >= NN) return;
    float acc = bf2f(hWs[n * HID + j]);
    int beg = row_ptr[n], end = row_ptr[n + 1];
    int e = beg;
    for (; e + 3 < end; e += 4) {
        int s0 = src_sorted[e], s1 = src_sorted[e + 1];
        int s2 = src_sorted[e + 2], s3 = src_sorted[e + 3];
        float h0 = bf2f(hWs[s0 * HID + j]);
        float h1 = bf2f(hWs[s1 * HID + j]);
        float h2 = bf2f(hWs[s2 * HID + j]);
        float h3 = bf2f(hWs[s3 * HID + j]);
        acc += (h0 + h1) + (h2 + h3);
    }
    for (; e < end; ++e) acc += bf2f(hWs[src_sorted[e] * HID + j]);
    out[n * HID + j] = fmaxf(fmaf(dinv[n], acc, b[j]), 0.0f);
}

// ---------------- pooling: segment starts, fused pool+head ----------------
__global__ __launch_bounds__(256) void k_bounds(const int* __restrict__ batch, int* __restrict__ start) {
    int i = blockIdx.x * 256 + threadIdx.x;
    if (i >= NN) return;
    int b = batch[i];
    if (i == 0) {
        for (int g = 0; g <= b; ++g) start[g] = 0;
    } else {
        int p = batch[i - 1];
        for (int g = p + 1; g <= b; ++g) start[g] = i;
    }
    if (i == NN - 1) {
        for (int g = b + 1; g <= NG; ++g) start[g] = NN;
    }
}

__global__ __launch_bounds__(256) void k_pool_head(const float* __restrict__ h, const int* __restrict__ start,
                                                   const float* __restrict__ Wc, const float* __restrict__ bc,
                                                   float* __restrict__ out) {
    __shared__ float part[4][HID];
    int g = blockIdx.x;
    int tid = threadIdx.x;
    int j = tid & 63, w = tid >> 6;
    int beg = start[g], end = start[g + 1];
    float acc = 0.0f;
    for (int n = beg + w; n < end; n += 4) acc += h[n * HID + j];
    part[w][j] = acc;
    __syncthreads();
    if (w == 0) {
        float s = part[0][j] + part[1][j] + part[2][j] + part[3][j];
        float cnt = (float)(end - beg);
        float p = s / fmaxf(cnt, 1.0f);
#pragma unroll
        for (int c = 0; c < NC; ++c) {
            float v = p * Wc[j * NC + c];
            for (int off = 32; off > 0; off >>= 1) v += __shfl_down(v, off);
            if (j == 0) out[g * NC + c] = v + bc[c];
        }
    }
}

// ---------------- driver ----------------
extern "C" void kernel_launch(void* const* d_in, const int* in_sizes, int n_in,
                              void* d_out, int out_size, void* d_ws, size_t ws_size,
                              hipStream_t stream) {
    const float* x  = (const float*)d_in[0];
    const int* ei   = (const int*)d_in[1];
    const int* bat  = (const int*)d_in[2];
    const float* W1 = (const float*)d_in[3];
    const float* b1 = (const float*)d_in[4];
    const float* W2 = (const float*)d_in[5];
    const float* b2 = (const float*)d_in[6];
    const float* W3 = (const float*)d_in[7];
    const float* b3 = (const float*)d_in[8];
    const float* Wc = (const float*)d_in[9];
    const float* bc = (const float*)d_in[10];
    float* out = (float*)d_out;

    const int* src = ei;
    const int* dst = ei + NE;

    char* wsb = (char*)d_ws;
    float* dinv      = (float*)wsb;                        // NN f32
    int*   cnt       = (int*)(wsb + 4 *  100000);          // NN
    int*   exc       = (int*)(wsb + 4 *  200000);          // NN
    int*   bsum      = (int*)(wsb + 4 *  300000);          // 512
    int*   row_ptr   = (int*)(wsb + 4 *  300512);          // NN+1
    int*   rank      = (int*)(wsb + 4 *  400516);          // NE
    int*   srcs      = (int*)(wsb + 4 * 1600516);          // NE
    unsigned short* hWs = (unsigned short*)(wsb + 4 * 2800516);  // NN*HID bf16 (12.8 MB)
    float* agg       = (float*)(wsb + 24002064);           // NN*HID f32 (16B aligned)
    int*   start     = (int*)(wsb + 49602064);             // NG+1

    const int gE = (NE + 255) / 256;  // 4688

    // CSR build + normalization
    k_zero_int<<<NB, 256, 0, stream>>>(cnt, NN);
    k_hist<<<gE, 256, 0, stream>>>(dst, cnt, rank);
    k_dinv<<<NB, 256, 0, stream>>>(cnt, dinv);
    k_scan1<<<NB, 256, 0, stream>>>(cnt, exc, bsum);
    k_scan2<<<1, 512, 0, stream>>>(bsum);
    k_scan3<<<NB, 256, 0, stream>>>(exc, bsum, row_ptr);
    k_bucket<<<gE, 256, 0, stream>>>(src, dst, row_ptr, rank, srcs);

    // layers
    k_gemm<IND, 32><<<(NN + 31) / 32, 256, 0, stream>>>(x, W1, dinv, hWs);
    k_aggregate<<<NN / 4, 256, 0, stream>>>(hWs, srcs, row_ptr, dinv, b1, agg);
    k_gemm<HID, 64><<<(NN + 63) / 64, 256, 0, stream>>>(agg, W2, dinv, hWs);
    k_aggregate<<<NN / 4, 256, 0, stream>>>(hWs, srcs, row_ptr, dinv, b2, agg);
    k_gemm<HID, 64><<<(NN + 63) / 64, 256, 0, stream>>>(agg, W3, dinv, hWs);
    k_aggregate<<<NN / 4, 256, 0, stream>>>(hWs, srcs, row_ptr, dinv, b3, agg);

    // pooling + head
    k_bounds<<<NB, 256, 0, stream>>>(bat, start);
    k_pool_head<<<NG, 256, 0, stream>>>(agg, start, Wc, bc, out);
}